// Round 4
// baseline (401.293 us; speedup 1.0000x reference)
//
#include <hip/hip_runtime.h>
#include <math.h>

// dims
#define BS 16
#define C_ 684
#define Hh 32
#define Ww 128
#define HW 4096
#define Qc 256
#define NP 512
#define Nn 256
#define NKT 26            // K-tiles of 32 (832 total: 684 x-ch + 121 taps + pad)
#define NSUP 13           // super-steps of 2 kt (one barrier each)
#define NB 64             // pixels per gemm block

// workspace layout (float offsets)
#define WS_BETA 0            // 16*4096 = 65536
#define WS_BIAS 65536        // 16*512  = 8192
#define WS_EEXP 73728        // 16*4096 = 65536
#define WS_ESUM 139264       // 16
#define WS_ASW  139280       // 26*4*512*8 shorts = 425984 shorts = 212992 floats
#define WS_CTXA 352272       // 16*684 = 10944 floats (atomic ctx accumulator)

typedef __attribute__((ext_vector_type(8))) short bf16x8;
typedef __attribute__((ext_vector_type(4))) float f32x4;

static __device__ __forceinline__ short f2bf(float f) {
    unsigned u = __builtin_bit_cast(unsigned, f);
    u += 0x7fff + ((u >> 16) & 1);          // RNE
    return (short)(u >> 16);
}

static __device__ __forceinline__ float fast_tanh(float v) {
    float ax = fabsf(v);
    float t = __expf(-2.f * ax);            // in (0,1], no overflow
    float th = (1.f - t) * __builtin_amdgcn_rcpf(1.f + t);
    return copysignf(th, v);
}

// ---- fused prep: beta, A-swizzle, bias, esum/ctxa-zero -----------------
__global__ void k_prep(const float* __restrict__ alpha, const float* __restrict__ ua,
                       const float* __restrict__ ufw, const float* __restrict__ qw,
                       const float* __restrict__ st, const float* __restrict__ waw,
                       const float* __restrict__ wab, const float* __restrict__ ufb,
                       const float* __restrict__ qb, const float* __restrict__ uab,
                       float* __restrict__ beta, short* __restrict__ a_sw,
                       float* __restrict__ bias, float* __restrict__ esum,
                       float* __restrict__ ctxa) {
    int part = blockIdx.x, tid = threadIdx.x;
    if (part < 256) {
        // beta = sum_t alpha
        int idx = part * 256 + tid;
        int b = idx >> 12, n = idx & 4095;
        const float* a = alpha + (size_t)b * 4 * HW + n;
        beta[idx] = a[0] + a[HW] + a[2 * HW] + a[3 * HW];
    } else if (part < 1920) {
        // a_sw[kt][g][m][j] = A[k][m] bf16, k = kt*32+g*8+j
        int idx = (part - 256) * 256 + tid;          // < 425984
        int j = idx & 7, m = (idx >> 3) & 511, g = (idx >> 12) & 3, kt = idx >> 14;
        int k = kt * 32 + g * 8 + j;
        float v = 0.f;
        if (k < C_) {
            v = ua[m * C_ + k];
        } else if (k < C_ + 121) {
            int tap = k - C_;
            const float* ur = ufw + m * Qc;
            float s = 0.f;
            for (int q = 0; q < Qc; ++q) s += ur[q] * qw[q * 121 + tap];
            v = s;
        }
        a_sw[idx] = f2bf(v);
    } else if (part < 1952) {
        // bias[b][p]
        int idx = (part - 1920) * 256 + tid;         // < 8192
        int b = idx >> 9, p = idx & 511;
        float s = wab[p] + ufb[p] + uab[p];
        const float* sv = st + b * Nn;
        const float* wr = waw + p * Nn;
        for (int n = 0; n < Nn; ++n) s += sv[n] * wr[n];
        const float* ur = ufw + p * Qc;
        for (int q = 0; q < Qc; ++q) s += ur[q] * qb[q];
        bias[idx] = s;
    } else {
        if (tid < BS) esum[tid] = 0.f;
        for (int i = tid; i < BS * C_; i += 256) ctxa[i] = 0.f;
    }
}

// ---- fused MFMA GEMM + tanh/Va/exp epilogue + atomic ctx partial -------
// block: M=512 x N=64, K=832. R0's proven dataflow (LDS-staged B, dbuf,
// dist-2 global prefetch, plain __syncthreads) with ONE change: BK=64
// super-steps — both kt halves packed into one 8KB slab, ONE barrier,
// then 64 MFMAs. Halves barrier count (26->13) and doubles the MFMA run
// per sync (m233: stage+barrier overhead dominates 2-phase loops) at
// identical register footprint (fv[2][8] = the two halves; bf[4]/af[8]
// reused per half; arch VGPR must stay <=128 so AGPR 128 keeps 2 w/SIMD).
__launch_bounds__(256, 2)
__global__ void k_gemm(const short* __restrict__ a_sw, const float* __restrict__ x,
                       const float* __restrict__ beta, const float* __restrict__ bias,
                       const float* __restrict__ vaw, const float* __restrict__ vab,
                       float* __restrict__ eexp, float* __restrict__ esum,
                       float* __restrict__ ctxa) {
    __shared__ short Bs[2][2 * 4 * NB * 8];  // 2 supers x 8 KB : [half][g][n][j]
    __shared__ float ered[4][NB];
    __shared__ float eeL[NB];

    const int tid = threadIdx.x;
    const int lane = tid & 63, wid = tid >> 6;
    const int b = blockIdx.y, n0 = blockIdx.x * NB;
    const int q = lane >> 4, r = lane & 15;

    // staging role: pixel sn, k-group sg (wave-uniform), 8 j's
    const int sn = tid & 63;
    const int sg = tid >> 6;
    const int n_glob = n0 + sn;
    const int pr = n_glob >> 7, pc = n_glob & 127;
    const float* xb = x + (size_t)b * C_ * HW + n_glob;
    const float* betab = beta + b * HW;

    f32x4 acc[8][4] = {};
    float fv[2][8];

    #define LDSTAGE(KT, DST)                                                  \
    {                                                                         \
        int kbase = (KT) * 32 + sg * 8;                                       \
        _Pragma("unroll")                                                     \
        for (int j = 0; j < 8; ++j) {                                         \
            int k = kbase + j;                                                \
            float f = 0.f;                                                    \
            if (k < C_) {                                                     \
                f = xb[(size_t)k * HW];                                       \
            } else if (k < C_ + 121) {                                        \
                int tap = k - C_;                                             \
                int di = tap / 11, dj = tap - di * 11;                        \
                int rr = pr + di - 5, cc = pc + dj - 5;                       \
                if (rr >= 0 && rr < Hh && cc >= 0 && cc < Ww)                 \
                    f = betab[rr * 128 + cc];                                 \
            }                                                                 \
            (DST)[j] = f;                                                     \
        }                                                                     \
    }

    // pack one 8-value half into its LDS slab slot
    #define PACKHALF(BUF, HALF, SRC)                                          \
    {                                                                         \
        const float* f = (SRC);                                               \
        unsigned pk[4];                                                       \
        _Pragma("unroll")                                                     \
        for (int h = 0; h < 4; ++h)                                           \
            pk[h] = (unsigned)(unsigned short)f2bf(f[2 * h]) |                \
                    ((unsigned)(unsigned short)f2bf(f[2 * h + 1]) << 16);     \
        *(uint4*)&Bs[BUF][(HALF) * 4 * NB * 8 + (sg * NB + sn) * 8] =         \
            make_uint4(pk[0], pk[1], pk[2], pk[3]);                           \
    }

    LDSTAGE(0, fv[0]);
    LDSTAGE(1, fv[1]);

    const short* ap = a_sw + (size_t)(q * NP + wid * 128 + r) * 8;

    for (int s = 0; s < NSUP; ++s) {
        const int buf = s & 1;

        // ---- A fragments for kt0 first: L2 latency covered by pack+barrier
        bf16x8 af[8];
        const short* ak0 = ap + (size_t)(2 * s) * 4 * NP * 8;
        #pragma unroll
        for (int ms = 0; ms < 8; ++ms)
            af[ms] = *(const bf16x8*)(ak0 + ms * 16 * 8);

        // ---- pack BOTH halves (prefetched last super) into the slab ----
        PACKHALF(buf, 0, fv[0]);
        PACKHALF(buf, 1, fv[1]);
        __syncthreads();   // single barrier per super (dbuf makes WAR safe)

        // ---- half 0: kt = 2s ----
        bf16x8 bf[4];
        #pragma unroll
        for (int ns = 0; ns < 4; ++ns)
            bf[ns] = *(const bf16x8*)&Bs[buf][(q * NB + ns * 16 + r) * 8];

        // prefetch staging values for super s+1 (overlaps the 64 MFMAs)
        if (s < NSUP - 1) {
            LDSTAGE(2 * s + 2, fv[0]);
            LDSTAGE(2 * s + 3, fv[1]);
        }

        __builtin_amdgcn_s_setprio(1);
        #pragma unroll
        for (int ms = 0; ms < 8; ++ms)
            #pragma unroll
            for (int ns = 0; ns < 4; ++ns)
                acc[ms][ns] = __builtin_amdgcn_mfma_f32_16x16x32_bf16(af[ms], bf[ns], acc[ms][ns], 0, 0, 0);
        __builtin_amdgcn_s_setprio(0);

        // ---- half 1: kt = 2s+1 ----
        const short* ak1 = ap + (size_t)(2 * s + 1) * 4 * NP * 8;
        #pragma unroll
        for (int ms = 0; ms < 8; ++ms)
            af[ms] = *(const bf16x8*)(ak1 + ms * 16 * 8);
        #pragma unroll
        for (int ns = 0; ns < 4; ++ns)
            bf[ns] = *(const bf16x8*)&Bs[buf][4 * NB * 8 + (q * NB + ns * 16 + r) * 8];

        __builtin_amdgcn_s_setprio(1);
        #pragma unroll
        for (int ms = 0; ms < 8; ++ms)
            #pragma unroll
            for (int ns = 0; ns < 4; ++ns)
                acc[ms][ns] = __builtin_amdgcn_mfma_f32_16x16x32_bf16(af[ms], bf[ns], acc[ms][ns], 0, 0, 0);
        __builtin_amdgcn_s_setprio(0);
    }
    #undef LDSTAGE
    #undef PACKHALF

    // ---- epilogue: e = sum_rows Va[row]*tanh(acc+bias[row]); exp; esum ----
    // C/D layout: col = lane&15, row = (lane>>4)*4 + reg
    float es[4] = {0.f, 0.f, 0.f, 0.f};
    #pragma unroll
    for (int ms = 0; ms < 8; ++ms) {
        #pragma unroll
        for (int reg = 0; reg < 4; ++reg) {
            int row = wid * 128 + ms * 16 + q * 4 + reg;
            float bv = bias[b * NP + row];
            float vv = vaw[row];
            #pragma unroll
            for (int ns = 0; ns < 4; ++ns)
                es[ns] += vv * fast_tanh(acc[ms][ns][reg] + bv);
        }
    }
    #pragma unroll
    for (int ns = 0; ns < 4; ++ns) {
        es[ns] += __shfl_xor(es[ns], 16, 64);
        es[ns] += __shfl_xor(es[ns], 32, 64);
    }
    if (lane < 16) {
        #pragma unroll
        for (int ns = 0; ns < 4; ++ns) ered[wid][ns * 16 + r] = es[ns];
    }
    __syncthreads();
    if (tid < NB) {          // exactly wave 0
        float s = ered[0][tid] + ered[1][tid] + ered[2][tid] + ered[3][tid] + vab[0];
        float ex = expf(s);
        eexp[b * HW + n0 + tid] = ex;
        eeL[tid] = ex;
        float ps = ex;
        #pragma unroll
        for (int off = 32; off > 0; off >>= 1) ps += __shfl_xor(ps, off, 64);
        if (tid == 0) atomicAdd(&esum[b], ps);
    }
    __syncthreads();

    // ---- unnormalized partial context over this block's 64 pixels ------
    for (int c = tid; c < C_; c += 256) {
        const float* xr = x + ((size_t)b * C_ + c) * HW + n0;
        float s = 0.f;
        #pragma unroll
        for (int n = 0; n < NB; n += 4) {
            float4 xv = *(const float4*)(xr + n);
            s += xv.x * eeL[n] + xv.y * eeL[n + 1] + xv.z * eeL[n + 2] + xv.w * eeL[n + 3];
        }
        atomicAdd(&ctxa[b * C_ + c], s);
    }
}

// ---- finish: scale ctx accumulator + alpha writeback -------------------
__global__ void k_finish(const float* __restrict__ eexp, const float* __restrict__ esum,
                         const float* __restrict__ ctxa, float* __restrict__ ctx,
                         float* __restrict__ aout) {
    int part = blockIdx.x, b = blockIdx.y, tid = threadIdx.x;
    float iv = 1.f / (esum[b] + 1e-8f);
    int c = part * 171 + tid;
    if (tid < 171 && c < C_) ctx[b * C_ + c] = ctxa[b * C_ + c] * iv;
    int k0 = part * 1024;
    for (int k = tid; k < 1024; k += 256)
        aout[b * HW + k0 + k] = eexp[b * HW + k0 + k] * iv;
}

extern "C" void kernel_launch(void* const* d_in, const int* in_sizes, int n_in,
                              void* d_out, int out_size, void* d_ws, size_t ws_size,
                              hipStream_t stream) {
    const float* x      = (const float*)d_in[0];
    const float* st     = (const float*)d_in[1];
    const float* alpha  = (const float*)d_in[2];
    const float* convQw = (const float*)d_in[3];
    const float* convQb = (const float*)d_in[4];
    const float* Waw    = (const float*)d_in[5];
    const float* Wab    = (const float*)d_in[6];
    const float* Uaw    = (const float*)d_in[7];
    const float* Uab    = (const float*)d_in[8];
    const float* Ufw    = (const float*)d_in[9];
    const float* Ufb    = (const float*)d_in[10];
    const float* Vaw    = (const float*)d_in[11];
    const float* Vab    = (const float*)d_in[12];

    float* ws   = (float*)d_ws;
    float* beta = ws + WS_BETA;
    float* bias = ws + WS_BIAS;
    float* eexp = ws + WS_EEXP;
    float* esum = ws + WS_ESUM;
    short* a_sw = (short*)(ws + WS_ASW);
    float* ctxa = ws + WS_CTXA;

    float* ctx  = (float*)d_out;             // [16, 684]
    float* aout = (float*)d_out + BS * C_;   // [16, 4096]

    k_prep<<<1953, 256, 0, stream>>>(alpha, Uaw, Ufw, convQw, st, Waw, Wab, Ufb,
                                     convQb, Uab, beta, a_sw, bias, esum, ctxa);
    k_gemm<<<dim3(HW / NB, BS), 256, 0, stream>>>(a_sw, x, beta, bias, Vaw, Vab,
                                                  eexp, esum, ctxa);
    k_finish<<<dim3(4, BS), 256, 0, stream>>>(eexp, esum, ctxa, ctx, aout);
}

// Round 5
// 352.536 us; speedup vs baseline: 1.1383x; 1.1383x over previous
//
#include <hip/hip_runtime.h>
#include <math.h>

// dims
#define BS 16
#define C_ 684
#define Hh 32
#define Ww 128
#define HW 4096
#define Qc 256
#define NP 512
#define Nn 256
#define NKT 26            // K-tiles of 32 (832 total: 684 x-ch + 121 taps + pad)
#define NB 128            // pixels per gemm block (8 waves: 4 M-quarters x 2 N-halves)

// workspace layout (float offsets)
#define WS_BETA 0            // 16*4096 = 65536
#define WS_BIAS 65536        // 16*512  = 8192
#define WS_EEXP 73728        // 16*4096 = 65536
#define WS_ESUM 139264       // 16
#define WS_ASW  139280       // 26*4*512*8 shorts = 425984 shorts = 212992 floats
#define WS_CTXA 352272       // 16*684 = 10944 floats (atomic ctx accumulator)

typedef __attribute__((ext_vector_type(8))) short bf16x8;
typedef __attribute__((ext_vector_type(4))) float f32x4;

static __device__ __forceinline__ short f2bf(float f) {
    unsigned u = __builtin_bit_cast(unsigned, f);
    u += 0x7fff + ((u >> 16) & 1);          // RNE
    return (short)(u >> 16);
}

static __device__ __forceinline__ float fast_tanh(float v) {
    float ax = fabsf(v);
    float t = __expf(-2.f * ax);            // in (0,1], no overflow
    float th = (1.f - t) * __builtin_amdgcn_rcpf(1.f + t);
    return copysignf(th, v);
}

// ---- fused prep: beta, A-swizzle, bias, esum/ctxa-zero -----------------
__global__ void k_prep(const float* __restrict__ alpha, const float* __restrict__ ua,
                       const float* __restrict__ ufw, const float* __restrict__ qw,
                       const float* __restrict__ st, const float* __restrict__ waw,
                       const float* __restrict__ wab, const float* __restrict__ ufb,
                       const float* __restrict__ qb, const float* __restrict__ uab,
                       float* __restrict__ beta, short* __restrict__ a_sw,
                       float* __restrict__ bias, float* __restrict__ esum,
                       float* __restrict__ ctxa) {
    int part = blockIdx.x, tid = threadIdx.x;
    if (part < 256) {
        // beta = sum_t alpha
        int idx = part * 256 + tid;
        int b = idx >> 12, n = idx & 4095;
        const float* a = alpha + (size_t)b * 4 * HW + n;
        beta[idx] = a[0] + a[HW] + a[2 * HW] + a[3 * HW];
    } else if (part < 1920) {
        // a_sw[kt][g][m][j] = A[k][m] bf16, k = kt*32+g*8+j
        int idx = (part - 256) * 256 + tid;          // < 425984
        int j = idx & 7, m = (idx >> 3) & 511, g = (idx >> 12) & 3, kt = idx >> 14;
        int k = kt * 32 + g * 8 + j;
        float v = 0.f;
        if (k < C_) {
            v = ua[m * C_ + k];
        } else if (k < C_ + 121) {
            int tap = k - C_;
            const float* ur = ufw + m * Qc;
            float s = 0.f;
            for (int q = 0; q < Qc; ++q) s += ur[q] * qw[q * 121 + tap];
            v = s;
        }
        a_sw[idx] = f2bf(v);
    } else if (part < 1952) {
        // bias[b][p]
        int idx = (part - 1920) * 256 + tid;         // < 8192
        int b = idx >> 9, p = idx & 511;
        float s = wab[p] + ufb[p] + uab[p];
        const float* sv = st + b * Nn;
        const float* wr = waw + p * Nn;
        for (int n = 0; n < Nn; ++n) s += sv[n] * wr[n];
        const float* ur = ufw + p * Qc;
        for (int q = 0; q < Qc; ++q) s += ur[q] * qb[q];
        bias[idx] = s;
    } else {
        if (tid < BS) esum[tid] = 0.f;
        for (int i = tid; i < BS * C_; i += 256) ctxa[i] = 0.f;
    }
}

// light workgroup barrier: ds_write visibility only — does NOT drain vmcnt,
// so the distance-2 global prefetch stays in flight across the barrier.
// Important now: 1 block/CU means no sibling block covers a vmcnt drain.
#define LIGHT_BARRIER()                                              \
    do {                                                             \
        asm volatile("s_waitcnt lgkmcnt(0)" ::: "memory");           \
        __builtin_amdgcn_sched_barrier(0);                           \
        __builtin_amdgcn_s_barrier();                                \
        asm volatile("" ::: "memory");                               \
        __builtin_amdgcn_sched_barrier(0);                           \
    } while (0)

// ---- fused MFMA GEMM + tanh/Va/exp epilogue + atomic ctx partial -------
// block: M=512 x N=128, K=832, 512 threads = 8 waves = (M-quarter mq,
// N-half nh). Per-wave dataflow IDENTICAL to the proven R0 loop (8 af
// loads, dist-2 f32 prefetch, pack->LDS dbuf, one light barrier/kt,
// 4x ds_read_b128, 32 MFMA into acc[8][4]=128 AGPR). The change is
// A-REUSE: the block's 832KB A-panel now serves 128 pixels instead of 64,
// halving total A read traffic (852->426 MB) — the term that R2's 2x-A
// regression (+100us) identified as dominant. Waves (mq, nh=0/1) pair on
// a SIMD and share af cachelines (L1-hit for the sibling).
__launch_bounds__(512, 2)
__global__ void k_gemm(const short* __restrict__ a_sw, const float* __restrict__ x,
                       const float* __restrict__ beta, const float* __restrict__ bias,
                       const float* __restrict__ vaw, const float* __restrict__ vab,
                       float* __restrict__ eexp, float* __restrict__ esum,
                       float* __restrict__ ctxa) {
    __shared__ short Bs[2][4 * NB * 8];  // 2 x 8 KB : [g][n][j]
    __shared__ float ered[2][4][64];     // [nh][mq][pixel-in-half]
    __shared__ float eeL[NB];

    const int tid = threadIdx.x;
    const int lane = tid & 63, wid = tid >> 6;
    const int mq = wid & 3, nh = wid >> 2;
    const int b = blockIdx.y, n0 = blockIdx.x * NB;
    const int q = lane >> 4, r = lane & 15;

    // staging role: pixel sn (0..127), k-group sg (wave-pair-uniform), 8 j's
    const int sn = tid & 127;
    const int sg = tid >> 7;
    // n0 is a multiple of 128 -> the block covers exactly one image row
    const int prow = blockIdx.x;             // image row (block-uniform)
    const float* xb = x + (size_t)b * C_ * HW + n0 + sn;
    const float* betab = beta + b * HW;

    f32x4 acc[8][4] = {};
    float fv[2][8];

    // pure-x fast path: valid for kt <= 20 (k max = 20*32+31 = 671 < 684)
    #define LDSTAGE_FAST(KT, DST)                                             \
    {                                                                         \
        const float* xk = xb + (size_t)((KT) * 32 + sg * 8) * HW;             \
        _Pragma("unroll")                                                     \
        for (int j = 0; j < 8; ++j) (DST)[j] = xk[(size_t)j * HW];            \
    }

    #define LDSTAGE(KT, DST)                                                  \
    {                                                                         \
        int kbase = (KT) * 32 + sg * 8;                                       \
        _Pragma("unroll")                                                     \
        for (int j = 0; j < 8; ++j) {                                         \
            int k = kbase + j;                                                \
            float f = 0.f;                                                    \
            if (k < C_) {                                                     \
                f = xb[(size_t)k * HW];                                       \
            } else if (k < C_ + 121) {                                        \
                int tap = k - C_;                                             \
                int di = tap / 11, dj = tap - di * 11;                        \
                int rr = prow + di - 5, cc = sn + dj - 5;                     \
                if (rr >= 0 && rr < Hh && cc >= 0 && cc < Ww)                 \
                    f = betab[rr * 128 + cc];                                 \
            }                                                                 \
            (DST)[j] = f;                                                     \
        }                                                                     \
    }

    LDSTAGE_FAST(0, fv[0]);
    LDSTAGE_FAST(1, fv[1]);

    const short* ap = a_sw + (size_t)(q * NP + mq * 128 + r) * 8;

    #pragma unroll 2
    for (int kt = 0; kt < NKT; ++kt) {
        // ---- A fragments first: L2 latency covered by pack+barrier+ds_read
        bf16x8 af[8];
        const short* ak = ap + (size_t)kt * 4 * NP * 8;
        #pragma unroll
        for (int ms = 0; ms < 8; ++ms)
            af[ms] = *(const bf16x8*)(ak + ms * 16 * 8);

        // ---- pack B values (prefetched 2 iters ago) and store to LDS ----
        {
            const float* f = fv[kt & 1];
            unsigned pk[4];
            #pragma unroll
            for (int h = 0; h < 4; ++h)
                pk[h] = (unsigned)(unsigned short)f2bf(f[2 * h]) |
                        ((unsigned)(unsigned short)f2bf(f[2 * h + 1]) << 16);
            *(uint4*)&Bs[kt & 1][(sg * NB + sn) * 8] = make_uint4(pk[0], pk[1], pk[2], pk[3]);
        }
        LIGHT_BARRIER();   // single barrier per kt (dbuf makes WAR safe); no vmcnt drain

        bf16x8 bf[4];
        #pragma unroll
        for (int ns = 0; ns < 4; ++ns)
            bf[ns] = *(const bf16x8*)&Bs[kt & 1][(q * NB + nh * 64 + ns * 16 + r) * 8];

        // prefetch staging values for kt+2 (overlaps with MFMA below)
        if (kt < NKT - 2) {
            if (kt <= 18) LDSTAGE_FAST(kt + 2, fv[kt & 1])
            else          LDSTAGE(kt + 2, fv[kt & 1])
        }

        #pragma unroll
        for (int ms = 0; ms < 8; ++ms)
            #pragma unroll
            for (int ns = 0; ns < 4; ++ns)
                acc[ms][ns] = __builtin_amdgcn_mfma_f32_16x16x32_bf16(af[ms], bf[ns], acc[ms][ns], 0, 0, 0);
    }
    #undef LDSTAGE
    #undef LDSTAGE_FAST

    // ---- epilogue: e = sum_rows Va[row]*tanh(acc+bias[row]); exp; esum ----
    // C/D layout: col = lane&15, row = (lane>>4)*4 + reg
    float es[4] = {0.f, 0.f, 0.f, 0.f};
    #pragma unroll
    for (int ms = 0; ms < 8; ++ms) {
        #pragma unroll
        for (int reg = 0; reg < 4; ++reg) {
            int row = mq * 128 + ms * 16 + q * 4 + reg;
            float bv = bias[b * NP + row];
            float vv = vaw[row];
            #pragma unroll
            for (int ns = 0; ns < 4; ++ns)
                es[ns] += vv * fast_tanh(acc[ms][ns][reg] + bv);
        }
    }
    #pragma unroll
    for (int ns = 0; ns < 4; ++ns) {
        es[ns] += __shfl_xor(es[ns], 16, 64);
        es[ns] += __shfl_xor(es[ns], 32, 64);
    }
    if (lane < 16) {
        #pragma unroll
        for (int ns = 0; ns < 4; ++ns) ered[nh][mq][ns * 16 + r] = es[ns];
    }
    __syncthreads();
    if (tid < NB) {          // waves 0 and 1
        int nh2 = tid >> 6, idx = tid & 63;
        float s = ered[nh2][0][idx] + ered[nh2][1][idx] + ered[nh2][2][idx]
                + ered[nh2][3][idx] + vab[0];
        float ex = expf(s);
        eexp[b * HW + n0 + tid] = ex;
        eeL[tid] = ex;
        float ps = ex;
        #pragma unroll
        for (int off = 32; off > 0; off >>= 1) ps += __shfl_xor(ps, off, 64);
        if ((tid & 63) == 0) atomicAdd(&esum[b], ps);
    }
    __syncthreads();

    // ---- unnormalized partial context over this block's 128 pixels -----
    for (int c = tid; c < C_; c += 512) {
        const float* xr = x + ((size_t)b * C_ + c) * HW + n0;
        float s = 0.f;
        #pragma unroll
        for (int n = 0; n < NB; n += 4) {
            float4 xv = *(const float4*)(xr + n);
            s += xv.x * eeL[n] + xv.y * eeL[n + 1] + xv.z * eeL[n + 2] + xv.w * eeL[n + 3];
        }
        atomicAdd(&ctxa[b * C_ + c], s);
    }
}

// ---- finish: scale ctx accumulator + alpha writeback -------------------
__global__ void k_finish(const float* __restrict__ eexp, const float* __restrict__ esum,
                         const float* __restrict__ ctxa, float* __restrict__ ctx,
                         float* __restrict__ aout) {
    int part = blockIdx.x, b = blockIdx.y, tid = threadIdx.x;
    float iv = 1.f / (esum[b] + 1e-8f);
    int c = part * 171 + tid;
    if (tid < 171 && c < C_) ctx[b * C_ + c] = ctxa[b * C_ + c] * iv;
    int k0 = part * 1024;
    for (int k = tid; k < 1024; k += 256)
        aout[b * HW + k0 + k] = eexp[b * HW + k0 + k] * iv;
}

extern "C" void kernel_launch(void* const* d_in, const int* in_sizes, int n_in,
                              void* d_out, int out_size, void* d_ws, size_t ws_size,
                              hipStream_t stream) {
    const float* x      = (const float*)d_in[0];
    const float* st     = (const float*)d_in[1];
    const float* alpha  = (const float*)d_in[2];
    const float* convQw = (const float*)d_in[3];
    const float* convQb = (const float*)d_in[4];
    const float* Waw    = (const float*)d_in[5];
    const float* Wab    = (const float*)d_in[6];
    const float* Uaw    = (const float*)d_in[7];
    const float* Uab    = (const float*)d_in[8];
    const float* Ufw    = (const float*)d_in[9];
    const float* Ufb    = (const float*)d_in[10];
    const float* Vaw    = (const float*)d_in[11];
    const float* Vab    = (const float*)d_in[12];

    float* ws   = (float*)d_ws;
    float* beta = ws + WS_BETA;
    float* bias = ws + WS_BIAS;
    float* eexp = ws + WS_EEXP;
    float* esum = ws + WS_ESUM;
    short* a_sw = (short*)(ws + WS_ASW);
    float* ctxa = ws + WS_CTXA;

    float* ctx  = (float*)d_out;             // [16, 684]
    float* aout = (float*)d_out + BS * C_;   // [16, 4096]

    k_prep<<<1953, 256, 0, stream>>>(alpha, Uaw, Ufw, convQw, st, Waw, Wab, Ufb,
                                     convQb, Uab, beta, a_sw, bias, esum, ctxa);
    k_gemm<<<dim3(HW / NB, BS), 512, 0, stream>>>(a_sw, x, beta, bias, Vaw, Vab,
                                                  eexp, esum, ctxa);
    k_finish<<<dim3(4, BS), 256, 0, stream>>>(eexp, esum, ctxa, ctx, aout);
}